// Round 1
// baseline (392.791 us; speedup 1.0000x reference)
//
#include <hip/hip_runtime.h>
#include <cstdint>
#include <type_traits>

// ReprogrammingLayer on MI355X (gfx950), round 1: correctness-first full bf16-MFMA pipeline.
// out = softmax((X@Wq)(S@Wk)^T/8) (V@Wv) @ Wo  with fp32 accumulate everywhere.

typedef unsigned short u16;
typedef __attribute__((ext_vector_type(8))) short bf16x8;   // 8 bf16 = 4 VGPR (MFMA A/B frag)
typedef __attribute__((ext_vector_type(4))) float f32x4;    // MFMA C/D frag
typedef __attribute__((ext_vector_type(4))) float fvec4;
typedef __attribute__((ext_vector_type(4))) unsigned short u16x4;

using gld_src_t = const __attribute__((address_space(1))) void*;
using gld_dst_t = __attribute__((address_space(3))) void*;

static __device__ __forceinline__ u16 bf16_rne(float f) {
  uint32_t u = __builtin_bit_cast(uint32_t, f);
  u += 0x7fffu + ((u >> 16) & 1u);          // round-to-nearest-even
  return (u16)(u >> 16);
}

// ---------------- fp32 -> bf16 convert with row padding (pad rows -> 0) ----------------
__global__ void convert_pad_bf16(const float* __restrict__ in, u16* __restrict__ out,
                                 int validR, int C, long n4) {
  long stride = (long)gridDim.x * blockDim.x;
  for (long i = (long)blockIdx.x * blockDim.x + threadIdx.x; i < n4; i += stride) {
    long e = i << 2;                 // element index (C % 4 == 0, never crosses rows)
    int r = (int)(e / C);
    u16x4 o;
    if (r < validR) {
      fvec4 v = *(const fvec4*)(in + e);
      o[0] = bf16_rne(v[0]); o[1] = bf16_rne(v[1]);
      o[2] = bf16_rne(v[2]); o[3] = bf16_rne(v[3]);
    } else {
      o[0] = 0; o[1] = 0; o[2] = 0; o[3] = 0;
    }
    *(u16x4*)(out + e) = o;
  }
}

// ---------------- transpose to bf16: in[R][C] (fp32 or bf16) -> out[C][R] bf16 ----------
template <bool F32IN>
__global__ void transpose_to_bf16(const void* __restrict__ inv, u16* __restrict__ out,
                                  int R, int C) {
  __shared__ u16 tile[32][33];       // +1 pad: conflict-free transpose
  int bc = blockIdx.x * 32, br = blockIdx.y * 32;
  int tx = threadIdx.x & 31, ty = threadIdx.x >> 5;   // 32 x 8
#pragma unroll
  for (int i = 0; i < 4; ++i) {
    int r = br + ty + i * 8, c = bc + tx;
    u16 bits = 0;
    if (r < R && c < C) {
      if constexpr (F32IN) bits = bf16_rne(((const float*)inv)[(size_t)r * C + c]);
      else                 bits = ((const u16*)inv)[(size_t)r * C + c];
    }
    tile[ty + i * 8][tx] = bits;
  }
  __syncthreads();
#pragma unroll
  for (int i = 0; i < 4; ++i) {
    int orow = bc + ty + i * 8, oc = br + tx;
    if (orow < C && oc < R) out[(size_t)orow * R + oc] = tile[tx][ty + i * 8];
  }
}

// ---------------- bf16 GEMM, m97 structure: C[M,N] = A[M,K] @ B[N,K]^T + bias ----------
// A, B row-major K-contiguous bf16. 128x128 tile, BK=32, 4 waves, global_load_lds staging.
// Dual pointer sets selected by blockIdx.z (used to fuse the K- and V-projections).
template <typename CT>
__global__ __launch_bounds__(256) void gemm_bt_128(
    const u16* __restrict__ A0, const u16* __restrict__ A1,
    const u16* __restrict__ B0, const u16* __restrict__ B1,
    const float* __restrict__ bias0, const float* __restrict__ bias1,
    CT* __restrict__ C0, CT* __restrict__ C1,
    int M, int N, int K) {
  const u16* A = blockIdx.z ? A1 : A0;
  const u16* B = blockIdx.z ? B1 : B0;
  const float* bias = blockIdx.z ? bias1 : bias0;
  CT* C = blockIdx.z ? C1 : C0;
  (void)M;

  __shared__ u16 As[128 * 32];   // 8 KB
  __shared__ u16 Bs[128 * 32];   // 8 KB

  const int tid = threadIdx.x;
  const int w = tid >> 6, lane = tid & 63;
  const int lr = lane & 15, lg = lane >> 4;
  const int bm = blockIdx.y * 128, bn = blockIdx.x * 128;
  const int wr = (w >> 1) * 64, wc = (w & 1) * 64;

  f32x4 acc[4][4] = {};

  const int nk = K >> 5;
  for (int kt = 0; kt < nk; ++kt) {
    // stage A+B tiles: 512 chunks of 16B each per tile; chunk c -> row c>>2, quarter c&3
#pragma unroll
    for (int j = 0; j < 2; ++j) {
      int cb = j * 256 + w * 64;            // wave-uniform chunk base
      int c = cb + lane;
      const u16* gA = A + (size_t)(bm + (c >> 2)) * K + (size_t)kt * 32 + (c & 3) * 8;
      __builtin_amdgcn_global_load_lds((gld_src_t)(const void*)gA,
                                       (gld_dst_t)(As + (size_t)cb * 8), 16, 0, 0);
      const u16* gB = B + (size_t)(bn + (c >> 2)) * K + (size_t)kt * 32 + (c & 3) * 8;
      __builtin_amdgcn_global_load_lds((gld_src_t)(const void*)gB,
                                       (gld_dst_t)(Bs + (size_t)cb * 8), 16, 0, 0);
    }
    __syncthreads();   // drains vmcnt for global_load_lds

    bf16x8 af[4], bfr[4];
#pragma unroll
    for (int m = 0; m < 4; ++m)
      af[m] = *(const bf16x8*)(As + (wr + m * 16 + lr) * 32 + lg * 8);
#pragma unroll
    for (int n = 0; n < 4; ++n)
      bfr[n] = *(const bf16x8*)(Bs + (wc + n * 16 + lr) * 32 + lg * 8);
#pragma unroll
    for (int m = 0; m < 4; ++m)
#pragma unroll
      for (int n = 0; n < 4; ++n)
        acc[m][n] = __builtin_amdgcn_mfma_f32_16x16x32_bf16(af[m], bfr[n], acc[m][n], 0, 0, 0);
    __syncthreads();   // protect LDS before next stage
  }

  // epilogue: C/D layout col=lane&15, row=(lane>>4)*4+reg  [m89/m91 verified]
#pragma unroll
  for (int n = 0; n < 4; ++n) {
    int col = bn + wc + n * 16 + lr;
    float bv = bias[col];
#pragma unroll
    for (int m = 0; m < 4; ++m) {
      int row0 = bm + wr + m * 16 + lg * 4;
#pragma unroll
      for (int r = 0; r < 4; ++r) {
        float v = acc[m][n][r] + bv;
        if constexpr (std::is_same<CT, u16>::value)
          C[(size_t)(row0 + r) * N + col] = bf16_rne(v);
        else
          C[(size_t)(row0 + r) * N + col] = v;
      }
    }
  }
}

// ---------------- fused attention ----------------
// grid (L/32, H, B), 256 threads. Block: 32 q-rows of one (b,h).
// Wave w handles s-columns [w*256, w*256+256). P (unnormalized, masked) staged in LDS.
__global__ __launch_bounds__(256) void attn_kernel(
    const u16* __restrict__ Q,   // [8192, 768] bf16
    const u16* __restrict__ Kb,  // [1024, 768] bf16 (rows >= 1000 defined but masked)
    const u16* __restrict__ VT,  // [768, 1024] bf16 (v transposed, head-major rows)
    u16* __restrict__ O) {       // [8192, 768] bf16
  constexpr int DM = 768, DH = 64, SPAD = 1024, SVAL = 1000, L = 1024;
  constexpr int PLD = 1032;      // +8 elem pad -> ds_read_b128 ~2-way (free)
  __shared__ u16 P[32 * PLD];    // 66,048 B (gfx950 allows >64KB static LDS)
  __shared__ float red[4][32];

  const int tid = threadIdx.x, w = tid >> 6, lane = tid & 63;
  const int lr = lane & 15, lg = lane >> 4;
  const int l0 = blockIdx.x * 32, h = blockIdx.y, b = blockIdx.z;

  // Q fragments (rows m*16+lr, k = kk*32 + lg*8 .. +8)
  const size_t qbase = ((size_t)b * L + l0) * DM + h * DH;
  bf16x8 qf[2][2];
#pragma unroll
  for (int m = 0; m < 2; ++m)
#pragma unroll
    for (int kk = 0; kk < 2; ++kk)
      qf[m][kk] = *(const bf16x8*)(Q + qbase + (size_t)(m * 16 + lr) * DM + kk * 32 + lg * 8);

  // ---- QK^T: acc[m][t], cols = sb + t*16 ----
  f32x4 acc[2][16] = {};
  const int sb = w * 256;
#pragma unroll
  for (int t = 0; t < 16; ++t) {
    const size_t krow = (size_t)(sb + t * 16 + lr) * DM + h * DH;
#pragma unroll
    for (int kk = 0; kk < 2; ++kk) {
      bf16x8 kf = *(const bf16x8*)(Kb + krow + kk * 32 + lg * 8);
      acc[0][t] = __builtin_amdgcn_mfma_f32_16x16x32_bf16(qf[0][kk], kf, acc[0][t], 0, 0, 0);
      acc[1][t] = __builtin_amdgcn_mfma_f32_16x16x32_bf16(qf[1][kk], kf, acc[1][t], 0, 0, 0);
    }
  }
#pragma unroll
  for (int m = 0; m < 2; ++m)
#pragma unroll
    for (int t = 0; t < 16; ++t)
      acc[m][t] = acc[m][t] * 0.125f;   // 1/sqrt(64), exact power of two

  // ---- row max (rows: m*16 + lg*4 + r) ----
  float mx[2][4];
#pragma unroll
  for (int m = 0; m < 2; ++m)
#pragma unroll
    for (int r = 0; r < 4; ++r) mx[m][r] = -3.0e38f;
#pragma unroll
  for (int t = 0; t < 16; ++t) {
    bool valid = (sb + t * 16 + lr) < SVAL;
#pragma unroll
    for (int m = 0; m < 2; ++m)
#pragma unroll
      for (int r = 0; r < 4; ++r)
        mx[m][r] = fmaxf(mx[m][r], valid ? acc[m][t][r] : -3.0e38f);
  }
#pragma unroll
  for (int d = 1; d < 16; d <<= 1)
#pragma unroll
    for (int m = 0; m < 2; ++m)
#pragma unroll
      for (int r = 0; r < 4; ++r)
        mx[m][r] = fmaxf(mx[m][r], __shfl_xor(mx[m][r], d, 64));
  if (lr == 0) {
#pragma unroll
    for (int m = 0; m < 2; ++m)
#pragma unroll
      for (int r = 0; r < 4; ++r) red[w][m * 16 + lg * 4 + r] = mx[m][r];
  }
  __syncthreads();
  float fmx[2][4];
#pragma unroll
  for (int m = 0; m < 2; ++m)
#pragma unroll
    for (int r = 0; r < 4; ++r) {
      int row = m * 16 + lg * 4 + r;
      fmx[m][r] = fmaxf(fmaxf(red[0][row], red[1][row]), fmaxf(red[2][row], red[3][row]));
    }

  // ---- P = exp(s - max), masked; partial sums; P -> LDS bf16 ----
  float sm[2][4] = {{0, 0, 0, 0}, {0, 0, 0, 0}};
#pragma unroll
  for (int t = 0; t < 16; ++t) {
    int sg = sb + t * 16 + lr;
    bool valid = sg < SVAL;
#pragma unroll
    for (int m = 0; m < 2; ++m)
#pragma unroll
      for (int r = 0; r < 4; ++r) {
        float p = valid ? __expf(acc[m][t][r] - fmx[m][r]) : 0.0f;
        sm[m][r] += p;
        P[(m * 16 + lg * 4 + r) * PLD + sg] = bf16_rne(p);
      }
  }
#pragma unroll
  for (int d = 1; d < 16; d <<= 1)
#pragma unroll
    for (int m = 0; m < 2; ++m)
#pragma unroll
      for (int r = 0; r < 4; ++r)
        sm[m][r] += __shfl_xor(sm[m][r], d, 64);
  __syncthreads();   // orders red reads above vs writes below; makes P visible
  if (lr == 0) {
#pragma unroll
    for (int m = 0; m < 2; ++m)
#pragma unroll
      for (int r = 0; r < 4; ++r) red[w][m * 16 + lg * 4 + r] = sm[m][r];
  }
  __syncthreads();
  float fsum[2][4];
#pragma unroll
  for (int m = 0; m < 2; ++m)
#pragma unroll
    for (int r = 0; r < 4; ++r) {
      int row = m * 16 + lg * 4 + r;
      fsum[m][r] = red[0][row] + red[1][row] + red[2][row] + red[3][row];
    }

  // ---- PV: wave w -> output col-tile w (cols h*64 + w*16 + lr) ----
  f32x4 oacc[2] = {};
  const size_t vtrow = (size_t)(h * DH + w * 16 + lr) * SPAD;
  for (int ks = 0; ks < 32; ++ks) {
    bf16x8 vf = *(const bf16x8*)(VT + vtrow + ks * 32 + lg * 8);
#pragma unroll
    for (int m = 0; m < 2; ++m) {
      bf16x8 pf = *(const bf16x8*)(P + (m * 16 + lr) * PLD + ks * 32 + lg * 8);
      oacc[m] = __builtin_amdgcn_mfma_f32_16x16x32_bf16(pf, vf, oacc[m], 0, 0, 0);
    }
  }

  // ---- normalize + store ----
#pragma unroll
  for (int m = 0; m < 2; ++m)
#pragma unroll
    for (int r = 0; r < 4; ++r) {
      int row = m * 16 + lg * 4 + r;
      float v = oacc[m][r] / fsum[m][r];
      O[((size_t)b * L + l0 + row) * DM + h * DH + w * 16 + lr] = bf16_rne(v);
    }
}

// ---------------- host ----------------
extern "C" void kernel_launch(void* const* d_in, const int* in_sizes, int n_in,
                              void* d_out, int out_size, void* d_ws, size_t ws_size,
                              hipStream_t stream) {
  (void)in_sizes; (void)n_in; (void)out_size; (void)ws_size;
  const float* target = (const float*)d_in[0];   // [8,1024,768]
  const float* source = (const float*)d_in[1];   // [1000,4096]
  const float* value  = (const float*)d_in[2];   // [1000,4096]
  const float* Wq = (const float*)d_in[3];       // [768,768]
  const float* bq = (const float*)d_in[4];
  const float* Wk = (const float*)d_in[5];       // [4096,768]
  const float* bk = (const float*)d_in[6];
  const float* Wv = (const float*)d_in[7];       // [4096,768]
  const float* bv = (const float*)d_in[8];
  const float* Wo = (const float*)d_in[9];       // [768,4096]
  const float* bo = (const float*)d_in[10];
  float* out = (float*)d_out;

  // ws carve (total ~75.6 MB)
  char* ws = (char*)d_ws;
  size_t off = 0;
  auto carve = [&](size_t bytes) { void* p = ws + off; off += (bytes + 255) & ~(size_t)255; return p; };
  u16* Xb  = (u16*)carve(8192ull * 768 * 2);   // target bf16
  u16* Sb  = (u16*)carve(1024ull * 4096 * 2);  // source bf16, padded
  u16* Vbi = (u16*)carve(1024ull * 4096 * 2);  // value bf16, padded
  u16* WqT = (u16*)carve(768ull * 768 * 2);
  u16* WkT = (u16*)carve(768ull * 4096 * 2);
  u16* WvT = (u16*)carve(768ull * 4096 * 2);
  u16* WoT = (u16*)carve(4096ull * 768 * 2);
  u16* Qb  = (u16*)carve(8192ull * 768 * 2);
  u16* Kp  = (u16*)carve(1024ull * 768 * 2);
  u16* Vp  = (u16*)carve(1024ull * 768 * 2);
  u16* VTp = (u16*)carve(768ull * 1024 * 2);
  u16* Ob  = (u16*)carve(8192ull * 768 * 2);

  // converts
  convert_pad_bf16<<<2048, 256, 0, stream>>>(target, Xb, 8192, 768, (8192ll * 768) / 4);
  convert_pad_bf16<<<2048, 256, 0, stream>>>(source, Sb, 1000, 4096, (1024ll * 4096) / 4);
  convert_pad_bf16<<<2048, 256, 0, stream>>>(value,  Vbi, 1000, 4096, (1024ll * 4096) / 4);
  // weight transposes: grid(C/32, R/32)
  transpose_to_bf16<true><<<dim3(24, 24),  256, 0, stream>>>(Wq, WqT, 768, 768);
  transpose_to_bf16<true><<<dim3(24, 128), 256, 0, stream>>>(Wk, WkT, 4096, 768);
  transpose_to_bf16<true><<<dim3(24, 128), 256, 0, stream>>>(Wv, WvT, 4096, 768);
  transpose_to_bf16<true><<<dim3(128, 24), 256, 0, stream>>>(Wo, WoT, 768, 4096);

  // projections
  gemm_bt_128<u16><<<dim3(6, 64, 1), 256, 0, stream>>>(Xb, Xb, WqT, WqT, bq, bq, Qb, Qb,
                                                       8192, 768, 768);
  gemm_bt_128<u16><<<dim3(6, 8, 2), 256, 0, stream>>>(Sb, Vbi, WkT, WvT, bk, bv, Kp, Vp,
                                                      1024, 768, 4096);
  transpose_to_bf16<false><<<dim3(24, 32), 256, 0, stream>>>(Vp, VTp, 1024, 768);

  // attention
  attn_kernel<<<dim3(32, 12, 8), 256, 0, stream>>>(Qb, Kp, VTp, Ob);

  // output projection -> fp32 d_out
  gemm_bt_128<float><<<dim3(32, 64, 1), 256, 0, stream>>>(Ob, Ob, WoT, WoT, bo, bo, out, out,
                                                          8192, 4096, 768);
}

// Round 4
// 340.974 us; speedup vs baseline: 1.1520x; 1.1520x over previous
//
#include <hip/hip_runtime.h>
#include <cstdint>
#include <type_traits>

// ReprogrammingLayer on MI355X (gfx950), round 2 (resubmit):
//  - flash-style attention (per-wave private swizzled P-LDS, online softmax, no main-loop barriers)
//  - split-K K/V projection with f32 partials staged in d_out (overwritten later)

typedef unsigned short u16;
typedef __attribute__((ext_vector_type(8))) short bf16x8;   // 8 bf16 = 4 VGPR (MFMA A/B frag)
typedef __attribute__((ext_vector_type(4))) float f32x4;    // MFMA C/D frag
typedef __attribute__((ext_vector_type(4))) float fvec4;
typedef __attribute__((ext_vector_type(4))) unsigned short u16x4;

using gld_src_t = const __attribute__((address_space(1))) void*;
using gld_dst_t = __attribute__((address_space(3))) void*;

static __device__ __forceinline__ u16 bf16_rne(float f) {
  uint32_t u = __builtin_bit_cast(uint32_t, f);
  u += 0x7fffu + ((u >> 16) & 1u);          // round-to-nearest-even
  return (u16)(u >> 16);
}

static __device__ __forceinline__ float exp2_fast(float x) {
  float r; asm("v_exp_f32 %0, %1" : "=v"(r) : "v"(x)); return r;   // HW exp2
}

// ---------------- fp32 -> bf16 convert with row padding (pad rows -> 0) ----------------
__global__ void convert_pad_bf16(const float* __restrict__ in, u16* __restrict__ out,
                                 int validR, int C, long n4) {
  long stride = (long)gridDim.x * blockDim.x;
  for (long i = (long)blockIdx.x * blockDim.x + threadIdx.x; i < n4; i += stride) {
    long e = i << 2;                 // element index (C % 4 == 0, never crosses rows)
    int r = (int)(e / C);
    u16x4 o;
    if (r < validR) {
      fvec4 v = *(const fvec4*)(in + e);
      o[0] = bf16_rne(v[0]); o[1] = bf16_rne(v[1]);
      o[2] = bf16_rne(v[2]); o[3] = bf16_rne(v[3]);
    } else {
      o[0] = 0; o[1] = 0; o[2] = 0; o[3] = 0;
    }
    *(u16x4*)(out + e) = o;
  }
}

// ---------------- transpose to bf16: in[R][C] (fp32 or bf16) -> out[C][R] bf16 ----------
template <bool F32IN>
__global__ void transpose_to_bf16(const void* __restrict__ inv, u16* __restrict__ out,
                                  int R, int C) {
  __shared__ u16 tile[32][33];       // +1 pad: conflict-free transpose
  int bc = blockIdx.x * 32, br = blockIdx.y * 32;
  int tx = threadIdx.x & 31, ty = threadIdx.x >> 5;   // 32 x 8
#pragma unroll
  for (int i = 0; i < 4; ++i) {
    int r = br + ty + i * 8, c = bc + tx;
    u16 bits = 0;
    if (r < R && c < C) {
      if constexpr (F32IN) bits = bf16_rne(((const float*)inv)[(size_t)r * C + c]);
      else                 bits = ((const u16*)inv)[(size_t)r * C + c];
    }
    tile[ty + i * 8][tx] = bits;
  }
  __syncthreads();
#pragma unroll
  for (int i = 0; i < 4; ++i) {
    int orow = bc + ty + i * 8, oc = br + tx;
    if (orow < C && oc < R) out[(size_t)orow * R + oc] = tile[tx][ty + i * 8];
  }
}

// ---------------- bf16 GEMM, m97 structure: C[M,N] = A[M,K] @ B[N,K]^T + bias ----------
template <typename CT>
__global__ __launch_bounds__(256) void gemm_bt_128(
    const u16* __restrict__ A0, const u16* __restrict__ A1,
    const u16* __restrict__ B0, const u16* __restrict__ B1,
    const float* __restrict__ bias0, const float* __restrict__ bias1,
    CT* __restrict__ C0, CT* __restrict__ C1,
    int M, int N, int K) {
  const u16* A = blockIdx.z ? A1 : A0;
  const u16* B = blockIdx.z ? B1 : B0;
  const float* bias = blockIdx.z ? bias1 : bias0;
  CT* C = blockIdx.z ? C1 : C0;
  (void)M;

  __shared__ u16 As[128 * 32];   // 8 KB
  __shared__ u16 Bs[128 * 32];   // 8 KB

  const int tid = threadIdx.x;
  const int w = tid >> 6, lane = tid & 63;
  const int lr = lane & 15, lg = lane >> 4;
  const int bm = blockIdx.y * 128, bn = blockIdx.x * 128;
  const int wr = (w >> 1) * 64, wc = (w & 1) * 64;

  f32x4 acc[4][4] = {};

  const int nk = K >> 5;
  for (int kt = 0; kt < nk; ++kt) {
#pragma unroll
    for (int j = 0; j < 2; ++j) {
      int cb = j * 256 + w * 64;            // wave-uniform chunk base
      int c = cb + lane;
      const u16* gA = A + (size_t)(bm + (c >> 2)) * K + (size_t)kt * 32 + (c & 3) * 8;
      __builtin_amdgcn_global_load_lds((gld_src_t)(const void*)gA,
                                       (gld_dst_t)(As + (size_t)cb * 8), 16, 0, 0);
      const u16* gB = B + (size_t)(bn + (c >> 2)) * K + (size_t)kt * 32 + (c & 3) * 8;
      __builtin_amdgcn_global_load_lds((gld_src_t)(const void*)gB,
                                       (gld_dst_t)(Bs + (size_t)cb * 8), 16, 0, 0);
    }
    __syncthreads();

    bf16x8 af[4], bfr[4];
#pragma unroll
    for (int m = 0; m < 4; ++m)
      af[m] = *(const bf16x8*)(As + (wr + m * 16 + lr) * 32 + lg * 8);
#pragma unroll
    for (int n = 0; n < 4; ++n)
      bfr[n] = *(const bf16x8*)(Bs + (wc + n * 16 + lr) * 32 + lg * 8);
#pragma unroll
    for (int m = 0; m < 4; ++m)
#pragma unroll
      for (int n = 0; n < 4; ++n)
        acc[m][n] = __builtin_amdgcn_mfma_f32_16x16x32_bf16(af[m], bfr[n], acc[m][n], 0, 0, 0);
    __syncthreads();
  }

#pragma unroll
  for (int n = 0; n < 4; ++n) {
    int col = bn + wc + n * 16 + lr;
    float bv = bias[col];
#pragma unroll
    for (int m = 0; m < 4; ++m) {
      int row0 = bm + wr + m * 16 + lg * 4;
#pragma unroll
      for (int r = 0; r < 4; ++r) {
        float v = acc[m][n][r] + bv;
        if constexpr (std::is_same<CT, u16>::value)
          C[(size_t)(row0 + r) * N + col] = bf16_rne(v);
        else
          C[(size_t)(row0 + r) * N + col] = v;
      }
    }
  }
}

// ---------------- split-K K/V projection: 8 z-blocks = {K,V} x 4 K-chunks of 1024 -------
// Writes f32 partials (no bias) to part[z][1024][768].
__global__ __launch_bounds__(256) void gemm_kv_splitk(
    const u16* __restrict__ Sb, const u16* __restrict__ Vbi,
    const u16* __restrict__ WkT, const u16* __restrict__ WvT,
    float* __restrict__ part) {
  const int z = blockIdx.z;
  const u16* A = (z >> 2) ? Vbi : Sb;     // [1024][4096]
  const u16* B = (z >> 2) ? WvT : WkT;    // [768][4096]
  float* C = part + (size_t)z * (1024 * 768);
  const int kofs = (z & 3) * 1024;

  __shared__ u16 As[128 * 32];
  __shared__ u16 Bs[128 * 32];
  const int tid = threadIdx.x, w = tid >> 6, lane = tid & 63;
  const int lr = lane & 15, lg = lane >> 4;
  const int bm = blockIdx.y * 128, bn = blockIdx.x * 128;
  const int wr = (w >> 1) * 64, wc = (w & 1) * 64;
  f32x4 acc[4][4] = {};

  for (int kt = 0; kt < 32; ++kt) {
#pragma unroll
    for (int j = 0; j < 2; ++j) {
      int cb = j * 256 + w * 64;
      int c = cb + lane;
      const u16* gA = A + (size_t)(bm + (c >> 2)) * 4096 + kofs + kt * 32 + (c & 3) * 8;
      __builtin_amdgcn_global_load_lds((gld_src_t)(const void*)gA,
                                       (gld_dst_t)(As + (size_t)cb * 8), 16, 0, 0);
      const u16* gB = B + (size_t)(bn + (c >> 2)) * 4096 + kofs + kt * 32 + (c & 3) * 8;
      __builtin_amdgcn_global_load_lds((gld_src_t)(const void*)gB,
                                       (gld_dst_t)(Bs + (size_t)cb * 8), 16, 0, 0);
    }
    __syncthreads();
    bf16x8 af[4], bfr[4];
#pragma unroll
    for (int m = 0; m < 4; ++m)
      af[m] = *(const bf16x8*)(As + (wr + m * 16 + lr) * 32 + lg * 8);
#pragma unroll
    for (int n = 0; n < 4; ++n)
      bfr[n] = *(const bf16x8*)(Bs + (wc + n * 16 + lr) * 32 + lg * 8);
#pragma unroll
    for (int m = 0; m < 4; ++m)
#pragma unroll
      for (int n = 0; n < 4; ++n)
        acc[m][n] = __builtin_amdgcn_mfma_f32_16x16x32_bf16(af[m], bfr[n], acc[m][n], 0, 0, 0);
    __syncthreads();
  }
#pragma unroll
  for (int n = 0; n < 4; ++n) {
    int col = bn + wc + n * 16 + lr;
#pragma unroll
    for (int m = 0; m < 4; ++m) {
      int row0 = bm + wr + m * 16 + lg * 4;
#pragma unroll
      for (int r = 0; r < 4; ++r)
        C[(size_t)(row0 + r) * 768 + col] = acc[m][n][r];
    }
  }
}

// ---------------- split-K reduce: partials + bias -> bf16 Kp / Vp ----------------------
__global__ __launch_bounds__(256) void kv_reduce(const float* __restrict__ part,
                                                 const float* __restrict__ bk,
                                                 const float* __restrict__ bv,
                                                 u16* __restrict__ Kp, u16* __restrict__ Vp) {
  const int mat = blockIdx.y;
  const long e = ((long)blockIdx.x * 256 + threadIdx.x) * 4;   // 768 blocks x 256 thr x 4 = 786432
  const float* p0 = part + (size_t)mat * 4 * 786432 + e;
  fvec4 s = *(const fvec4*)p0;
  s += *(const fvec4*)(p0 + 786432);
  s += *(const fvec4*)(p0 + 2 * 786432);
  s += *(const fvec4*)(p0 + 3 * 786432);
  const float* bias = mat ? bv : bk;
  int col = (int)(e % 768);
  fvec4 bb = *(const fvec4*)(bias + col);
  s += bb;
  u16x4 o;
  o[0] = bf16_rne(s[0]); o[1] = bf16_rne(s[1]); o[2] = bf16_rne(s[2]); o[3] = bf16_rne(s[3]);
  u16* dst = mat ? Vp : Kp;
  *(u16x4*)(dst + e) = o;
}

// ---------------- flash attention ----------------
// grid (32, 12, 8), 256 threads. Block: 32 q-rows of one (b,h). Wave w owns s-range
// [w*256, w*256+256) in 4 chunks of 64, online softmax, private swizzled P-LDS (dbuf),
// NO barriers in the main loop. End: 2-barrier cross-wave combine.
__global__ __launch_bounds__(256, 3) void attn_flash(
    const u16* __restrict__ Q,   // [8192, 768] bf16
    const u16* __restrict__ Kb,  // [1024, 768] bf16 (rows >= 1000 masked)
    const u16* __restrict__ VT,  // [768, 1024] bf16
    u16* __restrict__ O) {       // [8192, 768] bf16
  constexpr int DM = 768, DH = 64, SPAD = 1024, SVAL = 1000, L = 1024;
  constexpr float SCL = 0.18033688011112042f;   // (1/8) * log2(e)  -- exp2 domain
  // union: main loop -> P[4 waves][2 dbuf][4096 B swizzled]; combine -> obuf[4][32][68] f32
  __shared__ __align__(16) char smem[4 * 32 * 68 * 4];   // 34816 B
  __shared__ float redm[4][32];
  __shared__ float redl[4][32];

  const int tid = threadIdx.x, w = tid >> 6, lane = tid & 63;
  const int lr = lane & 15, lg = lane >> 4;
  const int l0 = blockIdx.x * 32, h = blockIdx.y, b = blockIdx.z;

  char* const pbase = smem + w * 8192;

  // Q fragments (A-operand: row = m*16+lr, k = kk*32 + lg*8 + e)
  const size_t qbase = ((size_t)b * L + l0) * DM + h * DH;
  bf16x8 qf[2][2];
#pragma unroll
  for (int m = 0; m < 2; ++m)
#pragma unroll
    for (int kk = 0; kk < 2; ++kk)
      qf[m][kk] = *(const bf16x8*)(Q + qbase + (size_t)(m * 16 + lr) * DM + kk * 32 + lg * 8);

  float m_run[2][4], l_run[2][4];
#pragma unroll
  for (int m = 0; m < 2; ++m)
#pragma unroll
    for (int r = 0; r < 4; ++r) { m_run[m][r] = -3.0e38f; l_run[m][r] = 0.0f; }
  f32x4 oacc[2][4] = {};

  const int sbase = w * 256;
  for (int c = 0; c < 4; ++c) {
    const int s0 = sbase + c * 64;
    // ---- QK^T chunk: cols s = s0 + t*16 + lr (B-operand rows) ----
    f32x4 acc[2][4] = {};
#pragma unroll
    for (int t = 0; t < 4; ++t) {
      const size_t krow = (size_t)(s0 + t * 16 + lr) * DM + h * DH;
#pragma unroll
      for (int kk = 0; kk < 2; ++kk) {
        bf16x8 kf = *(const bf16x8*)(Kb + krow + kk * 32 + lg * 8);
        acc[0][t] = __builtin_amdgcn_mfma_f32_16x16x32_bf16(qf[0][kk], kf, acc[0][t], 0, 0, 0);
        acc[1][t] = __builtin_amdgcn_mfma_f32_16x16x32_bf16(qf[1][kk], kf, acc[1][t], 0, 0, 0);
      }
    }
    // ---- scale to exp2-domain, mask, chunk max ----
    float cm[2][4];
#pragma unroll
    for (int m = 0; m < 2; ++m)
#pragma unroll
      for (int r = 0; r < 4; ++r) cm[m][r] = -3.0e38f;
#pragma unroll
    for (int t = 0; t < 4; ++t) {
      const bool valid = (s0 + t * 16 + lr) < SVAL;
#pragma unroll
      for (int m = 0; m < 2; ++m)
#pragma unroll
        for (int r = 0; r < 4; ++r) {
          float v = valid ? acc[m][t][r] * SCL : -3.0e38f;
          acc[m][t][r] = v;
          cm[m][r] = fmaxf(cm[m][r], v);
        }
    }
#pragma unroll
    for (int d = 1; d < 16; d <<= 1)
#pragma unroll
      for (int m = 0; m < 2; ++m)
#pragma unroll
        for (int r = 0; r < 4; ++r)
          cm[m][r] = fmaxf(cm[m][r], __shfl_xor(cm[m][r], d, 64));
    // ---- online rescale ----
    float fsc[2][4];
#pragma unroll
    for (int m = 0; m < 2; ++m)
#pragma unroll
      for (int r = 0; r < 4; ++r) {
        float mn = fmaxf(m_run[m][r], cm[m][r]);
        fsc[m][r] = exp2_fast(m_run[m][r] - mn);
        m_run[m][r] = mn;
      }
#pragma unroll
    for (int m = 0; m < 2; ++m)
#pragma unroll
      for (int n = 0; n < 4; ++n)
#pragma unroll
        for (int r = 0; r < 4; ++r) oacc[m][n][r] *= fsc[m][r];
    // ---- P = exp2(s - m), write to private swizzled LDS, chunk sum ----
    char* const pc = pbase + (c & 1) * 4096;
    float cs[2][4] = {};
#pragma unroll
    for (int t = 0; t < 4; ++t)
#pragma unroll
      for (int m = 0; m < 2; ++m)
#pragma unroll
        for (int r = 0; r < 4; ++r) {
          float p = exp2_fast(acc[m][t][r] - m_run[m][r]);   // masked -> exp2(-3e38) = 0
          cs[m][r] += p;
          const int row = m * 16 + lg * 4 + r;
          const int byte = row * 128 + (((t * 16 + lr) * 2) ^ ((row & 7) << 4));
          *(u16*)(pc + byte) = bf16_rne(p);
        }
#pragma unroll
    for (int d = 1; d < 16; d <<= 1)
#pragma unroll
      for (int m = 0; m < 2; ++m)
#pragma unroll
        for (int r = 0; r < 4; ++r) cs[m][r] += __shfl_xor(cs[m][r], d, 64);
#pragma unroll
    for (int m = 0; m < 2; ++m)
#pragma unroll
      for (int r = 0; r < 4; ++r) l_run[m][r] = l_run[m][r] * fsc[m][r] + cs[m][r];
    // ---- PV chunk (same-wave LDS ordering: compiler lgkmcnt, no barrier) ----
#pragma unroll
    for (int ks = 0; ks < 2; ++ks) {
      bf16x8 pf[2];
#pragma unroll
      for (int m = 0; m < 2; ++m) {
        const int row = m * 16 + lr;
        pf[m] = *(const bf16x8*)(pc + row * 128 + ((ks * 64 + lg * 16) ^ ((row & 7) << 4)));
      }
#pragma unroll
      for (int n = 0; n < 4; ++n) {
        bf16x8 vf = *(const bf16x8*)(VT + (size_t)(h * DH + n * 16 + lr) * SPAD + s0 + ks * 32 + lg * 8);
        oacc[0][n] = __builtin_amdgcn_mfma_f32_16x16x32_bf16(pf[0], vf, oacc[0][n], 0, 0, 0);
        oacc[1][n] = __builtin_amdgcn_mfma_f32_16x16x32_bf16(pf[1], vf, oacc[1][n], 0, 0, 0);
      }
    }
  }

  // ---- cross-wave combine ----
  if (lr == 0) {
#pragma unroll
    for (int m = 0; m < 2; ++m)
#pragma unroll
      for (int r = 0; r < 4; ++r) {
        redm[w][m * 16 + lg * 4 + r] = m_run[m][r];
        redl[w][m * 16 + lg * 4 + r] = l_run[m][r];
      }
  }
  __syncthreads();
  float fown[2][4], lt[2][4];
#pragma unroll
  for (int m = 0; m < 2; ++m)
#pragma unroll
    for (int r = 0; r < 4; ++r) {
      const int row = m * 16 + lg * 4 + r;
      float M = fmaxf(fmaxf(redm[0][row], redm[1][row]), fmaxf(redm[2][row], redm[3][row]));
      lt[m][r] = redl[0][row] * exp2_fast(redm[0][row] - M)
               + redl[1][row] * exp2_fast(redm[1][row] - M)
               + redl[2][row] * exp2_fast(redm[2][row] - M)
               + redl[3][row] * exp2_fast(redm[3][row] - M);
      fown[m][r] = exp2_fast(m_run[m][r] - M);
    }
  float (*obuf)[32][68] = (float (*)[32][68])smem;   // P region dead; padded stride 68
#pragma unroll
  for (int m = 0; m < 2; ++m)
#pragma unroll
    for (int n = 0; n < 4; ++n)
#pragma unroll
      for (int r = 0; r < 4; ++r)
        obuf[w][m * 16 + lg * 4 + r][n * 16 + lr] = oacc[m][n][r] * fown[m][r];
  __syncthreads();
#pragma unroll
  for (int m = 0; m < 2; ++m)
#pragma unroll
    for (int r = 0; r < 4; ++r) {
      const int row = m * 16 + lg * 4 + r;
      float s = obuf[0][row][w * 16 + lr] + obuf[1][row][w * 16 + lr]
              + obuf[2][row][w * 16 + lr] + obuf[3][row][w * 16 + lr];
      O[((size_t)b * L + l0 + row) * DM + h * DH + w * 16 + lr] = bf16_rne(s / lt[m][r]);
    }
}

// ---------------- host ----------------
extern "C" void kernel_launch(void* const* d_in, const int* in_sizes, int n_in,
                              void* d_out, int out_size, void* d_ws, size_t ws_size,
                              hipStream_t stream) {
  (void)in_sizes; (void)n_in; (void)out_size; (void)ws_size;
  const float* target = (const float*)d_in[0];   // [8,1024,768]
  const float* source = (const float*)d_in[1];   // [1000,4096]
  const float* value  = (const float*)d_in[2];   // [1000,4096]
  const float* Wq = (const float*)d_in[3];       // [768,768]
  const float* bq = (const float*)d_in[4];
  const float* Wk = (const float*)d_in[5];       // [4096,768]
  const float* bk = (const float*)d_in[6];
  const float* Wv = (const float*)d_in[7];       // [4096,768]
  const float* bv = (const float*)d_in[8];
  const float* Wo = (const float*)d_in[9];       // [768,4096]
  const float* bo = (const float*)d_in[10];
  float* out = (float*)d_out;

  char* ws = (char*)d_ws;
  size_t off = 0;
  auto carve = [&](size_t bytes) { void* p = ws + off; off += (bytes + 255) & ~(size_t)255; return p; };
  u16* Xb  = (u16*)carve(8192ull * 768 * 2);
  u16* Sb  = (u16*)carve(1024ull * 4096 * 2);
  u16* Vbi = (u16*)carve(1024ull * 4096 * 2);
  u16* WqT = (u16*)carve(768ull * 768 * 2);
  u16* WkT = (u16*)carve(768ull * 4096 * 2);
  u16* WvT = (u16*)carve(768ull * 4096 * 2);
  u16* WoT = (u16*)carve(4096ull * 768 * 2);
  u16* Qb  = (u16*)carve(8192ull * 768 * 2);
  u16* Kp  = (u16*)carve(1024ull * 768 * 2);
  u16* Vp  = (u16*)carve(1024ull * 768 * 2);
  u16* VTp = (u16*)carve(768ull * 1024 * 2);
  u16* Ob  = (u16*)carve(8192ull * 768 * 2);

  // converts + weight transposes
  convert_pad_bf16<<<2048, 256, 0, stream>>>(target, Xb, 8192, 768, (8192ll * 768) / 4);
  convert_pad_bf16<<<2048, 256, 0, stream>>>(source, Sb, 1000, 4096, (1024ll * 4096) / 4);
  convert_pad_bf16<<<2048, 256, 0, stream>>>(value,  Vbi, 1000, 4096, (1024ll * 4096) / 4);
  transpose_to_bf16<true><<<dim3(24, 24),  256, 0, stream>>>(Wq, WqT, 768, 768);
  transpose_to_bf16<true><<<dim3(24, 128), 256, 0, stream>>>(Wk, WkT, 4096, 768);
  transpose_to_bf16<true><<<dim3(24, 128), 256, 0, stream>>>(Wv, WvT, 4096, 768);
  transpose_to_bf16<true><<<dim3(128, 24), 256, 0, stream>>>(Wo, WoT, 768, 4096);

  // K/V projection: split-K partials into d_out (scratch; fully overwritten at the end)
  gemm_kv_splitk<<<dim3(6, 8, 8), 256, 0, stream>>>(Sb, Vbi, WkT, WvT, out);
  kv_reduce<<<dim3(768, 2), 256, 0, stream>>>(out, bk, bv, Kp, Vp);
  transpose_to_bf16<false><<<dim3(24, 32), 256, 0, stream>>>(Vp, VTp, 1024, 768);

  // Q projection
  gemm_bt_128<u16><<<dim3(6, 64, 1), 256, 0, stream>>>(Xb, Xb, WqT, WqT, bq, bq, Qb, Qb,
                                                       8192, 768, 768);

  // attention
  attn_flash<<<dim3(32, 12, 8), 256, 0, stream>>>(Qb, Kp, VTp, Ob);

  // output projection -> fp32 d_out
  gemm_bt_128<float><<<dim3(32, 64, 1), 256, 0, stream>>>(Ob, Ob, WoT, WoT, bo, bo, out, out,
                                                          8192, 4096, 768);
}

// Round 6
// 232.741 us; speedup vs baseline: 1.6877x; 1.4650x over previous
//
#include <hip/hip_runtime.h>
#include <cstdint>
#include <type_traits>

// ReprogrammingLayer on MI355X (gfx950), round 5 (compile-fixed):
//  - swapped-QK^T flash attention (32x32x16 MFMA, P in registers, LDS-staged K/V, defer-max)
//  - scale folded into Q projection; split-K K/V projection unchanged (proven).

typedef unsigned short u16;
typedef __attribute__((ext_vector_type(8))) short bf16x8;    // 8 bf16 = 4 VGPR (MFMA A/B frag)
typedef __attribute__((ext_vector_type(4))) float f32x4;     // 16x16 MFMA C/D frag
typedef __attribute__((ext_vector_type(16))) float f32x16;   // 32x32 MFMA C/D frag
typedef __attribute__((ext_vector_type(4))) float fvec4;
typedef __attribute__((ext_vector_type(4))) unsigned short u16x4;
typedef __attribute__((ext_vector_type(4))) unsigned int u32x4;
typedef __attribute__((ext_vector_type(2))) unsigned int u32x2;

using gld_src_t = const __attribute__((address_space(1))) void*;
using gld_dst_t = __attribute__((address_space(3))) void*;

static __device__ __forceinline__ u16 bf16_rne(float f) {
  uint32_t u = __builtin_bit_cast(uint32_t, f);
  u += 0x7fffu + ((u >> 16) & 1u);          // round-to-nearest-even
  return (u16)(u >> 16);
}

static __device__ __forceinline__ float exp2_fast(float x) {
  float r; asm("v_exp_f32 %0, %1" : "=v"(r) : "v"(x)); return r;   // HW exp2
}

static __device__ __forceinline__ uint32_t pk_bf16(float a, float b) {
  return (uint32_t)bf16_rne(a) | ((uint32_t)bf16_rne(b) << 16);   // a -> low, b -> high
}

// ---------------- fp32 -> bf16 convert with row padding (pad rows -> 0) ----------------
__global__ void convert_pad_bf16(const float* __restrict__ in, u16* __restrict__ out,
                                 int validR, int C, long n4) {
  long stride = (long)gridDim.x * blockDim.x;
  for (long i = (long)blockIdx.x * blockDim.x + threadIdx.x; i < n4; i += stride) {
    long e = i << 2;
    int r = (int)(e / C);
    u16x4 o;
    if (r < validR) {
      fvec4 v = *(const fvec4*)(in + e);
      o[0] = bf16_rne(v[0]); o[1] = bf16_rne(v[1]);
      o[2] = bf16_rne(v[2]); o[3] = bf16_rne(v[3]);
    } else {
      o[0] = 0; o[1] = 0; o[2] = 0; o[3] = 0;
    }
    *(u16x4*)(out + e) = o;
  }
}

// ---------------- transpose to bf16: in[R][C] (fp32 or bf16) -> out[C][R] bf16 ----------
template <bool F32IN>
__global__ void transpose_to_bf16(const void* __restrict__ inv, u16* __restrict__ out,
                                  int R, int C) {
  __shared__ u16 tile[32][33];
  int bc = blockIdx.x * 32, br = blockIdx.y * 32;
  int tx = threadIdx.x & 31, ty = threadIdx.x >> 5;
#pragma unroll
  for (int i = 0; i < 4; ++i) {
    int r = br + ty + i * 8, c = bc + tx;
    u16 bits = 0;
    if (r < R && c < C) {
      if constexpr (F32IN) bits = bf16_rne(((const float*)inv)[(size_t)r * C + c]);
      else                 bits = ((const u16*)inv)[(size_t)r * C + c];
    }
    tile[ty + i * 8][tx] = bits;
  }
  __syncthreads();
#pragma unroll
  for (int i = 0; i < 4; ++i) {
    int orow = bc + ty + i * 8, oc = br + tx;
    if (orow < C && oc < R) out[(size_t)orow * R + oc] = tile[tx][ty + i * 8];
  }
}

// ---------------- bf16 GEMM, m97 structure: C[M,N] = (A[M,K] @ B[N,K]^T + bias)*escale --
template <typename CT>
__global__ __launch_bounds__(256) void gemm_bt_128(
    const u16* __restrict__ A0, const u16* __restrict__ A1,
    const u16* __restrict__ B0, const u16* __restrict__ B1,
    const float* __restrict__ bias0, const float* __restrict__ bias1,
    CT* __restrict__ C0, CT* __restrict__ C1,
    int M, int N, int K, float escale) {
  const u16* A = blockIdx.z ? A1 : A0;
  const u16* B = blockIdx.z ? B1 : B0;
  const float* bias = blockIdx.z ? bias1 : bias0;
  CT* C = blockIdx.z ? C1 : C0;
  (void)M;

  __shared__ u16 As[128 * 32];
  __shared__ u16 Bs[128 * 32];

  const int tid = threadIdx.x;
  const int w = tid >> 6, lane = tid & 63;
  const int lr = lane & 15, lg = lane >> 4;
  const int bm = blockIdx.y * 128, bn = blockIdx.x * 128;
  const int wr = (w >> 1) * 64, wc = (w & 1) * 64;

  f32x4 acc[4][4] = {};

  const int nk = K >> 5;
  for (int kt = 0; kt < nk; ++kt) {
#pragma unroll
    for (int j = 0; j < 2; ++j) {
      int cb = j * 256 + w * 64;
      int c = cb + lane;
      const u16* gA = A + (size_t)(bm + (c >> 2)) * K + (size_t)kt * 32 + (c & 3) * 8;
      __builtin_amdgcn_global_load_lds((gld_src_t)(const void*)gA,
                                       (gld_dst_t)(As + (size_t)cb * 8), 16, 0, 0);
      const u16* gB = B + (size_t)(bn + (c >> 2)) * K + (size_t)kt * 32 + (c & 3) * 8;
      __builtin_amdgcn_global_load_lds((gld_src_t)(const void*)gB,
                                       (gld_dst_t)(Bs + (size_t)cb * 8), 16, 0, 0);
    }
    __syncthreads();

    bf16x8 af[4], bfr[4];
#pragma unroll
    for (int m = 0; m < 4; ++m)
      af[m] = *(const bf16x8*)(As + (wr + m * 16 + lr) * 32 + lg * 8);
#pragma unroll
    for (int n = 0; n < 4; ++n)
      bfr[n] = *(const bf16x8*)(Bs + (wc + n * 16 + lr) * 32 + lg * 8);
#pragma unroll
    for (int m = 0; m < 4; ++m)
#pragma unroll
      for (int n = 0; n < 4; ++n)
        acc[m][n] = __builtin_amdgcn_mfma_f32_16x16x32_bf16(af[m], bfr[n], acc[m][n], 0, 0, 0);
    __syncthreads();
  }

#pragma unroll
  for (int n = 0; n < 4; ++n) {
    int col = bn + wc + n * 16 + lr;
    float bv = bias[col];
#pragma unroll
    for (int m = 0; m < 4; ++m) {
      int row0 = bm + wr + m * 16 + lg * 4;
#pragma unroll
      for (int r = 0; r < 4; ++r) {
        float v = (acc[m][n][r] + bv) * escale;
        if constexpr (std::is_same<CT, u16>::value)
          C[(size_t)(row0 + r) * N + col] = bf16_rne(v);
        else
          C[(size_t)(row0 + r) * N + col] = v;
      }
    }
  }
}

// ---------------- split-K K/V projection: 8 z-blocks = {K,V} x 4 K-chunks of 1024 -------
__global__ __launch_bounds__(256) void gemm_kv_splitk(
    const u16* __restrict__ Sb, const u16* __restrict__ Vbi,
    const u16* __restrict__ WkT, const u16* __restrict__ WvT,
    float* __restrict__ part) {
  const int z = blockIdx.z;
  const u16* A = (z >> 2) ? Vbi : Sb;
  const u16* B = (z >> 2) ? WvT : WkT;
  float* C = part + (size_t)z * (1024 * 768);
  const int kofs = (z & 3) * 1024;

  __shared__ u16 As[128 * 32];
  __shared__ u16 Bs[128 * 32];
  const int tid = threadIdx.x, w = tid >> 6, lane = tid & 63;
  const int lr = lane & 15, lg = lane >> 4;
  const int bm = blockIdx.y * 128, bn = blockIdx.x * 128;
  const int wr = (w >> 1) * 64, wc = (w & 1) * 64;
  f32x4 acc[4][4] = {};

  for (int kt = 0; kt < 32; ++kt) {
#pragma unroll
    for (int j = 0; j < 2; ++j) {
      int cb = j * 256 + w * 64;
      int c = cb + lane;
      const u16* gA = A + (size_t)(bm + (c >> 2)) * 4096 + kofs + kt * 32 + (c & 3) * 8;
      __builtin_amdgcn_global_load_lds((gld_src_t)(const void*)gA,
                                       (gld_dst_t)(As + (size_t)cb * 8), 16, 0, 0);
      const u16* gB = B + (size_t)(bn + (c >> 2)) * 4096 + kofs + kt * 32 + (c & 3) * 8;
      __builtin_amdgcn_global_load_lds((gld_src_t)(const void*)gB,
                                       (gld_dst_t)(Bs + (size_t)cb * 8), 16, 0, 0);
    }
    __syncthreads();
    bf16x8 af[4], bfr[4];
#pragma unroll
    for (int m = 0; m < 4; ++m)
      af[m] = *(const bf16x8*)(As + (wr + m * 16 + lr) * 32 + lg * 8);
#pragma unroll
    for (int n = 0; n < 4; ++n)
      bfr[n] = *(const bf16x8*)(Bs + (wc + n * 16 + lr) * 32 + lg * 8);
#pragma unroll
    for (int m = 0; m < 4; ++m)
#pragma unroll
      for (int n = 0; n < 4; ++n)
        acc[m][n] = __builtin_amdgcn_mfma_f32_16x16x32_bf16(af[m], bfr[n], acc[m][n], 0, 0, 0);
    __syncthreads();
  }
#pragma unroll
  for (int n = 0; n < 4; ++n) {
    int col = bn + wc + n * 16 + lr;
#pragma unroll
    for (int m = 0; m < 4; ++m) {
      int row0 = bm + wr + m * 16 + lg * 4;
#pragma unroll
      for (int r = 0; r < 4; ++r)
        C[(size_t)(row0 + r) * 768 + col] = acc[m][n][r];
    }
  }
}

// ---------------- split-K reduce: partials + bias -> bf16 Kp / Vp ----------------------
__global__ __launch_bounds__(256) void kv_reduce(const float* __restrict__ part,
                                                 const float* __restrict__ bk,
                                                 const float* __restrict__ bv,
                                                 u16* __restrict__ Kp, u16* __restrict__ Vp) {
  const int mat = blockIdx.y;
  const long e = ((long)blockIdx.x * 256 + threadIdx.x) * 4;
  const float* p0 = part + (size_t)mat * 4 * 786432 + e;
  fvec4 s = *(const fvec4*)p0;
  s += *(const fvec4*)(p0 + 786432);
  s += *(const fvec4*)(p0 + 2 * 786432);
  s += *(const fvec4*)(p0 + 3 * 786432);
  const float* bias = mat ? bv : bk;
  int col = (int)(e % 768);
  fvec4 bb = *(const fvec4*)(bias + col);
  s += bb;
  u16x4 o;
  o[0] = bf16_rne(s[0]); o[1] = bf16_rne(s[1]); o[2] = bf16_rne(s[2]); o[3] = bf16_rne(s[3]);
  u16* dst = mat ? Vp : Kp;
  *(u16x4*)(dst + e) = o;
}

// ---------------- swapped-QK^T flash attention ----------------
// grid (64, 12), 256 threads. Block: 128 q-rows of one head; wave owns 32 q-rows
// (q = lane&31). S-loop: 16 block-wide chunks of 64, K/VT tiles staged in LDS via
// global_load_lds (XOR-swizzled source + read). QK^T computed SWAPPED (A=K, B=Q) so
// each lane holds P-column values for ONE q-row: softmax is in-lane + 1 shfl. P is
// repacked in-register into the PV B-operand (out^T = VT * P^T). Defer-max (THR=8).
// Q is pre-scaled by (1/8)*log2(e) at the Q projection.
__global__ __launch_bounds__(256, 3) void attn_flash(
    const u16* __restrict__ Q,   // [8192, 768] bf16, pre-scaled
    const u16* __restrict__ Kb,  // [1024, 768] bf16 (rows >= 1000 are zero-padded)
    const u16* __restrict__ VT,  // [768, 1024] bf16
    u16* __restrict__ O) {       // [8192, 768] bf16
  constexpr int DM = 768, SPAD = 1024;
  __shared__ u16 Ks[2][64 * 64];    // [chunk s][d], swizzled, 8 KB per buf
  __shared__ u16 VTs[2][64 * 64];   // [d][chunk s], swizzled, 8 KB per buf

  const int tid = threadIdx.x, w = tid >> 6, lane = tid & 63;
  const int q5 = lane & 31, hi = lane >> 5, l7 = lane & 7;
  const int h = blockIdx.y;
  const int qrow = blockIdx.x * 128 + w * 32 + q5;

  // Q B-fragments: col=q (lane&31), k=d = dstep*16 + hi*8 + e
  bf16x8 qf[4];
#pragma unroll
  for (int dstep = 0; dstep < 4; ++dstep)
    qf[dstep] = *(const bf16x8*)(Q + (size_t)qrow * DM + h * 64 + dstep * 16 + hi * 8);

  // staging: 64 rows x 128 B per tile; slot = it*256 + w*64 + lane -> (row=slot>>3, c=slot&7)
  // LDS holds global 16B-chunk (c ^ (row&7)) at linear slot -> read applies the same XOR.
  auto STAGE = [&](int ch, int buf) {
#pragma unroll
    for (int it = 0; it < 2; ++it) {
      int slot = it * 256 + w * 64 + lane;
      int row = slot >> 3;
      int cg = (slot & 7) ^ (row & 7);
      __builtin_amdgcn_global_load_lds(
          (gld_src_t)(const void*)(Kb + (size_t)(ch * 64 + row) * DM + h * 64 + cg * 8),
          (gld_dst_t)(&Ks[buf][(size_t)(it * 256 + w * 64) * 8]), 16, 0, 0);
      __builtin_amdgcn_global_load_lds(
          (gld_src_t)(const void*)(VT + (size_t)(h * 64 + row) * SPAD + ch * 64 + cg * 8),
          (gld_dst_t)(&VTs[buf][(size_t)(it * 256 + w * 64) * 8]), 16, 0, 0);
    }
  };

  STAGE(0, 0);
  __syncthreads();

  float m_run = -3.0e38f, l_part = 0.0f;
  f32x16 oa0 = {}, oa1 = {};

  for (int ch = 0; ch < 16; ++ch) {
    const int cur = ch & 1;
    if (ch < 15) STAGE(ch + 1, cur ^ 1);

    const char* kbase = (const char*)&Ks[cur][0];
    const char* vbase = (const char*)&VTs[cur][0];

    // ---- QK^T (swapped): s-tiles st in {0,1}; C[s][q], lane holds 16 s for q=lane&31 ----
    f32x16 sc0 = {}, sc1 = {};
#pragma unroll
    for (int dstep = 0; dstep < 4; ++dstep) {
      const int colb = (dstep * 32 + hi * 16);
      bf16x8 kf0 = *(const bf16x8*)(kbase + (size_t)q5 * 128 + (colb ^ (l7 << 4)));
      bf16x8 kf1 = *(const bf16x8*)(kbase + (size_t)(32 + q5) * 128 + (colb ^ (l7 << 4)));
      sc0 = __builtin_amdgcn_mfma_f32_32x32x16_bf16(kf0, qf[dstep], sc0, 0, 0, 0);
      sc1 = __builtin_amdgcn_mfma_f32_32x32x16_bf16(kf1, qf[dstep], sc1, 0, 0, 0);
    }
    // mask: only chunk 15, s-tile 1, regs r>=4 map to s >= 1000 (s = 992 + (r&3)+8*(r>>2)+4*hi)
    if (ch == 15) {
#pragma unroll
      for (int r = 4; r < 16; ++r) sc1[r] = -3.0e38f;
    }

    // ---- chunk max (in-lane tree + pair combine) ----
    float mi = sc0[0];
#pragma unroll
    for (int r = 1; r < 16; ++r) mi = fmaxf(mi, sc0[r]);
#pragma unroll
    for (int r = 0; r < 16; ++r) mi = fmaxf(mi, sc1[r]);
    float cm = fmaxf(mi, __shfl_xor(mi, 32, 64));

    // ---- defer-max rescale ----
    if (__any(cm > m_run + 8.0f)) {
      float mn = fmaxf(m_run, cm);
      float fsc = exp2_fast(m_run - mn);
      m_run = mn;
      l_part *= fsc;
#pragma unroll
      for (int r = 0; r < 16; ++r) { oa0[r] *= fsc; oa1[r] *= fsc; }
    }

    // ---- P = exp2(s - m), per-lane partial sum (deferred reduce) ----
#pragma unroll
    for (int r = 0; r < 16; ++r) {
      float p0 = exp2_fast(sc0[r] - m_run); l_part += p0; sc0[r] = p0;
      float p1 = exp2_fast(sc1[r] - m_run); l_part += p1; sc1[r] = p1;
    }

    // ---- PV: out^T[d][q] += VT[d][s] * P^T[s][q]; B-frag built in-register ----
#pragma unroll
    for (int st = 0; st < 2; ++st) {
#pragma unroll
      for (int ks = 0; ks < 2; ++ks) {
        float pv0, pv1, pv2, pv3, pv4, pv5, pv6, pv7;
        if (st == 0) {
          if (ks == 0) { pv0=sc0[0];pv1=sc0[1];pv2=sc0[2];pv3=sc0[3];pv4=sc0[4];pv5=sc0[5];pv6=sc0[6];pv7=sc0[7]; }
          else         { pv0=sc0[8];pv1=sc0[9];pv2=sc0[10];pv3=sc0[11];pv4=sc0[12];pv5=sc0[13];pv6=sc0[14];pv7=sc0[15]; }
        } else {
          if (ks == 0) { pv0=sc1[0];pv1=sc1[1];pv2=sc1[2];pv3=sc1[3];pv4=sc1[4];pv5=sc1[5];pv6=sc1[6];pv7=sc1[7]; }
          else         { pv0=sc1[8];pv1=sc1[9];pv2=sc1[10];pv3=sc1[11];pv4=sc1[12];pv5=sc1[13];pv6=sc1[14];pv7=sc1[15]; }
        }
        uint32_t a = pk_bf16(pv0, pv1), b = pk_bf16(pv2, pv3);
        uint32_t c = pk_bf16(pv4, pv5), d = pk_bf16(pv6, pv7);
        uint32_t sa = (uint32_t)__shfl_xor((int)a, 32, 64);
        uint32_t sb = (uint32_t)__shfl_xor((int)b, 32, 64);
        uint32_t sc_ = (uint32_t)__shfl_xor((int)c, 32, 64);
        uint32_t sd = (uint32_t)__shfl_xor((int)d, 32, 64);
        u32x4 jw;
        jw[0] = hi ? sc_ : a;
        jw[1] = hi ? sd  : b;
        jw[2] = hi ? c   : sa;
        jw[3] = hi ? d   : sb;
        bf16x8 pB = __builtin_bit_cast(bf16x8, jw);
        const int colb = (st * 64 + ks * 32 + hi * 16);
#pragma unroll
        for (int dt = 0; dt < 2; ++dt) {
          bf16x8 vtf = *(const bf16x8*)(vbase + (size_t)(dt * 32 + q5) * 128 + (colb ^ (l7 << 4)));
          if (dt == 0) oa0 = __builtin_amdgcn_mfma_f32_32x32x16_bf16(vtf, pB, oa0, 0, 0, 0);
          else         oa1 = __builtin_amdgcn_mfma_f32_32x32x16_bf16(vtf, pB, oa1, 0, 0, 0);
        }
      }
    }
    __syncthreads();   // stage(ch+1) drained (vmcnt0) + all waves done reading cur
  }

  // ---- epilogue: combine pair sums, normalize, packed 8B stores ----
  float ool = 1.0f / (l_part + __shfl_xor(l_part, 32, 64));
  u16* obase = O + (size_t)qrow * DM + h * 64;
#pragma unroll
  for (int dt = 0; dt < 2; ++dt) {
#pragma unroll
    for (int g = 0; g < 4; ++g) {
      float v0, v1, v2, v3;
      if (dt == 0) { v0 = oa0[4*g]; v1 = oa0[4*g+1]; v2 = oa0[4*g+2]; v3 = oa0[4*g+3]; }
      else         { v0 = oa1[4*g]; v1 = oa1[4*g+1]; v2 = oa1[4*g+2]; v3 = oa1[4*g+3]; }
      u32x2 st2;
      st2[0] = pk_bf16(v0 * ool, v1 * ool);
      st2[1] = pk_bf16(v2 * ool, v3 * ool);
      *(u32x2*)(obase + dt * 32 + g * 8 + hi * 4) = st2;
    }
  }
}

// ---------------- host ----------------
extern "C" void kernel_launch(void* const* d_in, const int* in_sizes, int n_in,
                              void* d_out, int out_size, void* d_ws, size_t ws_size,
                              hipStream_t stream) {
  (void)in_sizes; (void)n_in; (void)out_size; (void)ws_size;
  const float* target = (const float*)d_in[0];
  const float* source = (const float*)d_in[1];
  const float* value  = (const float*)d_in[2];
  const float* Wq = (const float*)d_in[3];
  const float* bq = (const float*)d_in[4];
  const float* Wk = (const float*)d_in[5];
  const float* bk = (const float*)d_in[6];
  const float* Wv = (const float*)d_in[7];
  const float* bv = (const float*)d_in[8];
  const float* Wo = (const float*)d_in[9];
  const float* bo = (const float*)d_in[10];
  float* out = (float*)d_out;

  char* ws = (char*)d_ws;
  size_t off = 0;
  auto carve = [&](size_t bytes) { void* p = ws + off; off += (bytes + 255) & ~(size_t)255; return p; };
  u16* Xb  = (u16*)carve(8192ull * 768 * 2);
  u16* Sb  = (u16*)carve(1024ull * 4096 * 2);
  u16* Vbi = (u16*)carve(1024ull * 4096 * 2);
  u16* WqT = (u16*)carve(768ull * 768 * 2);
  u16* WkT = (u16*)carve(768ull * 4096 * 2);
  u16* WvT = (u16*)carve(768ull * 4096 * 2);
  u16* WoT = (u16*)carve(4096ull * 768 * 2);
  u16* Qb  = (u16*)carve(8192ull * 768 * 2);
  u16* Kp  = (u16*)carve(1024ull * 768 * 2);
  u16* Vp  = (u16*)carve(1024ull * 768 * 2);
  u16* VTp = (u16*)carve(768ull * 1024 * 2);
  u16* Ob  = (u16*)carve(8192ull * 768 * 2);

  const float SCL = 0.18033688011112042f;   // (1/8) * log2(e): exp2-domain scores

  convert_pad_bf16<<<2048, 256, 0, stream>>>(target, Xb, 8192, 768, (8192ll * 768) / 4);
  convert_pad_bf16<<<2048, 256, 0, stream>>>(source, Sb, 1000, 4096, (1024ll * 4096) / 4);
  convert_pad_bf16<<<2048, 256, 0, stream>>>(value,  Vbi, 1000, 4096, (1024ll * 4096) / 4);
  transpose_to_bf16<true><<<dim3(24, 24),  256, 0, stream>>>(Wq, WqT, 768, 768);
  transpose_to_bf16<true><<<dim3(24, 128), 256, 0, stream>>>(Wk, WkT, 4096, 768);
  transpose_to_bf16<true><<<dim3(24, 128), 256, 0, stream>>>(Wv, WvT, 4096, 768);
  transpose_to_bf16<true><<<dim3(128, 24), 256, 0, stream>>>(Wo, WoT, 768, 4096);

  gemm_kv_splitk<<<dim3(6, 8, 8), 256, 0, stream>>>(Sb, Vbi, WkT, WvT, out);
  kv_reduce<<<dim3(768, 2), 256, 0, stream>>>(out, bk, bv, Kp, Vp);
  transpose_to_bf16<false><<<dim3(24, 32), 256, 0, stream>>>(Vp, VTp, 1024, 768);

  // Q projection with exp2-domain scale folded in
  gemm_bt_128<u16><<<dim3(6, 64, 1), 256, 0, stream>>>(Xb, Xb, WqT, WqT, bq, bq, Qb, Qb,
                                                       8192, 768, 768, SCL);

  attn_flash<<<dim3(64, 12), 256, 0, stream>>>(Qb, Kp, VTp, Ob);

  gemm_bt_128<float><<<dim3(32, 64, 1), 256, 0, stream>>>(Ob, Ob, WoT, WoT, bo, bo, out, out,
                                                          8192, 4096, 768, 1.0f);
}

// Round 7
// 225.768 us; speedup vs baseline: 1.7398x; 1.0309x over previous
//
#include <hip/hip_runtime.h>
#include <cstdint>
#include <type_traits>

// ReprogrammingLayer on MI355X (gfx950), round 7:
//  - O-projection upgraded to 256x256-tile BK=64 8-wave prefetch-pipelined GEMM
//    (swizzled LDS, 1 barrier per K-tile, setprio around MFMA clusters, XCD swizzle)
//  - everything else identical to round 6 (passed, 233 us).

typedef unsigned short u16;
typedef __attribute__((ext_vector_type(8))) short bf16x8;    // 8 bf16 = 4 VGPR (MFMA A/B frag)
typedef __attribute__((ext_vector_type(4))) float f32x4;     // 16x16 MFMA C/D frag
typedef __attribute__((ext_vector_type(16))) float f32x16;   // 32x32 MFMA C/D frag
typedef __attribute__((ext_vector_type(4))) float fvec4;
typedef __attribute__((ext_vector_type(4))) unsigned short u16x4;
typedef __attribute__((ext_vector_type(4))) unsigned int u32x4;
typedef __attribute__((ext_vector_type(2))) unsigned int u32x2;

using gld_src_t = const __attribute__((address_space(1))) void*;
using gld_dst_t = __attribute__((address_space(3))) void*;

static __device__ __forceinline__ u16 bf16_rne(float f) {
  uint32_t u = __builtin_bit_cast(uint32_t, f);
  u += 0x7fffu + ((u >> 16) & 1u);          // round-to-nearest-even
  return (u16)(u >> 16);
}

static __device__ __forceinline__ float exp2_fast(float x) {
  float r; asm("v_exp_f32 %0, %1" : "=v"(r) : "v"(x)); return r;   // HW exp2
}

static __device__ __forceinline__ uint32_t pk_bf16(float a, float b) {
  return (uint32_t)bf16_rne(a) | ((uint32_t)bf16_rne(b) << 16);   // a -> low, b -> high
}

// ---------------- fp32 -> bf16 convert with row padding (pad rows -> 0) ----------------
__global__ void convert_pad_bf16(const float* __restrict__ in, u16* __restrict__ out,
                                 int validR, int C, long n4) {
  long stride = (long)gridDim.x * blockDim.x;
  for (long i = (long)blockIdx.x * blockDim.x + threadIdx.x; i < n4; i += stride) {
    long e = i << 2;
    int r = (int)(e / C);
    u16x4 o;
    if (r < validR) {
      fvec4 v = *(const fvec4*)(in + e);
      o[0] = bf16_rne(v[0]); o[1] = bf16_rne(v[1]);
      o[2] = bf16_rne(v[2]); o[3] = bf16_rne(v[3]);
    } else {
      o[0] = 0; o[1] = 0; o[2] = 0; o[3] = 0;
    }
    *(u16x4*)(out + e) = o;
  }
}

// ---------------- transpose to bf16: in[R][C] (fp32 or bf16) -> out[C][R] bf16 ----------
template <bool F32IN>
__global__ void transpose_to_bf16(const void* __restrict__ inv, u16* __restrict__ out,
                                  int R, int C) {
  __shared__ u16 tile[32][33];
  int bc = blockIdx.x * 32, br = blockIdx.y * 32;
  int tx = threadIdx.x & 31, ty = threadIdx.x >> 5;
#pragma unroll
  for (int i = 0; i < 4; ++i) {
    int r = br + ty + i * 8, c = bc + tx;
    u16 bits = 0;
    if (r < R && c < C) {
      if constexpr (F32IN) bits = bf16_rne(((const float*)inv)[(size_t)r * C + c]);
      else                 bits = ((const u16*)inv)[(size_t)r * C + c];
    }
    tile[ty + i * 8][tx] = bits;
  }
  __syncthreads();
#pragma unroll
  for (int i = 0; i < 4; ++i) {
    int orow = bc + ty + i * 8, oc = br + tx;
    if (orow < C && oc < R) out[(size_t)orow * R + oc] = tile[tx][ty + i * 8];
  }
}

// ---------------- bf16 GEMM, m97 structure (used for Q-proj; small grids) --------------
template <typename CT>
__global__ __launch_bounds__(256) void gemm_bt_128(
    const u16* __restrict__ A0, const u16* __restrict__ A1,
    const u16* __restrict__ B0, const u16* __restrict__ B1,
    const float* __restrict__ bias0, const float* __restrict__ bias1,
    CT* __restrict__ C0, CT* __restrict__ C1,
    int M, int N, int K, float escale) {
  const u16* A = blockIdx.z ? A1 : A0;
  const u16* B = blockIdx.z ? B1 : B0;
  const float* bias = blockIdx.z ? bias1 : bias0;
  CT* C = blockIdx.z ? C1 : C0;
  (void)M;

  __shared__ u16 As[128 * 32];
  __shared__ u16 Bs[128 * 32];

  const int tid = threadIdx.x;
  const int w = tid >> 6, lane = tid & 63;
  const int lr = lane & 15, lg = lane >> 4;
  const int bm = blockIdx.y * 128, bn = blockIdx.x * 128;
  const int wr = (w >> 1) * 64, wc = (w & 1) * 64;

  f32x4 acc[4][4] = {};

  const int nk = K >> 5;
  for (int kt = 0; kt < nk; ++kt) {
#pragma unroll
    for (int j = 0; j < 2; ++j) {
      int cb = j * 256 + w * 64;
      int c = cb + lane;
      const u16* gA = A + (size_t)(bm + (c >> 2)) * K + (size_t)kt * 32 + (c & 3) * 8;
      __builtin_amdgcn_global_load_lds((gld_src_t)(const void*)gA,
                                       (gld_dst_t)(As + (size_t)cb * 8), 16, 0, 0);
      const u16* gB = B + (size_t)(bn + (c >> 2)) * K + (size_t)kt * 32 + (c & 3) * 8;
      __builtin_amdgcn_global_load_lds((gld_src_t)(const void*)gB,
                                       (gld_dst_t)(Bs + (size_t)cb * 8), 16, 0, 0);
    }
    __syncthreads();

    bf16x8 af[4], bfr[4];
#pragma unroll
    for (int m = 0; m < 4; ++m)
      af[m] = *(const bf16x8*)(As + (wr + m * 16 + lr) * 32 + lg * 8);
#pragma unroll
    for (int n = 0; n < 4; ++n)
      bfr[n] = *(const bf16x8*)(Bs + (wc + n * 16 + lr) * 32 + lg * 8);
#pragma unroll
    for (int m = 0; m < 4; ++m)
#pragma unroll
      for (int n = 0; n < 4; ++n)
        acc[m][n] = __builtin_amdgcn_mfma_f32_16x16x32_bf16(af[m], bfr[n], acc[m][n], 0, 0, 0);
    __syncthreads();
  }

#pragma unroll
  for (int n = 0; n < 4; ++n) {
    int col = bn + wc + n * 16 + lr;
    float bv = bias[col];
#pragma unroll
    for (int m = 0; m < 4; ++m) {
      int row0 = bm + wr + m * 16 + lg * 4;
#pragma unroll
      for (int r = 0; r < 4; ++r) {
        float v = (acc[m][n][r] + bv) * escale;
        if constexpr (std::is_same<CT, u16>::value)
          C[(size_t)(row0 + r) * N + col] = bf16_rne(v);
        else
          C[(size_t)(row0 + r) * N + col] = v;
      }
    }
  }
}

// ---------------- 256x256-tile BK=64 pipelined GEMM (O-projection) ---------------------
// C[M,N] fp32 = A[M,K]bf16 @ B[N,K]^T bf16 + bias. 512 threads = 8 waves (2Mx4N),
// per-wave 128x64 output (acc[8][4]). LDS 128 KB: A/B tiles [256][64] double-buffered,
// XOR-swizzled ((row&7) 16B-chunk swizzle, staged via pre-swizzled global source).
// Per K-tile: issue all 8 prefetch gload_lds for t+1 -> other buffer, then 4 quadrant
// phases of ds_read+16 MFMA, then one __syncthreads (vmcnt drain is hidden by compute).
__global__ __launch_bounds__(512, 2) void gemm_bt_256(
    const u16* __restrict__ A, const u16* __restrict__ B,
    const float* __restrict__ bias, float* __restrict__ C,
    int M, int N, int K) {
  __shared__ u16 As[2][256 * 64];   // 2 x 32 KB
  __shared__ u16 Bs[2][256 * 64];   // 2 x 32 KB
  (void)M;

  const int tid = threadIdx.x, lane = tid & 63, w = tid >> 6;
  const int lr = lane & 15, lg = lane >> 4;
  const int wr = w >> 2, wcol = w & 3;          // 2 wave-rows x 4 wave-cols

  // XCD-aware bijective swizzle (grid = 512 blocks, 512 % 8 == 0)
  const int nbx = N >> 8;
  const int bid = blockIdx.y * gridDim.x + blockIdx.x;
  const int cpx = (gridDim.x * gridDim.y) >> 3;
  const int swz = (bid & 7) * cpx + (bid >> 3);
  const int bm = (swz / nbx) * 256, bn = (swz % nbx) * 256;

  f32x4 acc[8][4] = {};

  // stage K-tile t into buf: per thread 8 x 16B. Source chunk pre-swizzled so the
  // linear LDS write lands data such that read-side XOR recovers it.
  auto STAGE = [&](int t, int buf) {
#pragma unroll
    for (int h = 0; h < 2; ++h)
#pragma unroll
      for (int it = 0; it < 2; ++it) {
        const int s = it * 512 + tid;          // slot within half [0,1024)
        const int r = s >> 3;                  // row within half [0,128)
        const int cg = (s & 7) ^ (r & 7);      // pre-swizzled 16B chunk
        const int row = h * 128 + r;
        const int ldsb = h * 16384 + (it * 512 + w * 64) * 16;   // wave-uniform base
        __builtin_amdgcn_global_load_lds(
            (gld_src_t)(const void*)(A + (size_t)(bm + row) * K + t * 64 + cg * 8),
            (gld_dst_t)((char*)&As[buf][0] + ldsb), 16, 0, 0);
        __builtin_amdgcn_global_load_lds(
            (gld_src_t)(const void*)(B + (size_t)(bn + row) * K + t * 64 + cg * 8),
            (gld_dst_t)((char*)&Bs[buf][0] + ldsb), 16, 0, 0);
      }
  };

  // swizzled fragment read: row R, 16B-aligned colbyte CB
  auto LDF = [&](const u16* base, int R, int CB) {
    return *(const bf16x8*)((const char*)base + (size_t)R * 128 + (CB ^ ((R & 7) << 4)));
  };

  STAGE(0, 0);
  __syncthreads();

  const int nk = K >> 6;
  for (int t = 0; t < nk; ++t) {
    const int cur = t & 1;
    if (t + 1 < nk) STAGE(t + 1, cur ^ 1);
    const u16* as = &As[cur][0];
    const u16* bs = &Bs[cur][0];

    bf16x8 bfrag[4][2];
#pragma unroll
    for (int nf = 0; nf < 4; ++nf)
#pragma unroll
      for (int kk = 0; kk < 2; ++kk)
        bfrag[nf][kk] = LDF(bs, wcol * 64 + nf * 16 + lr, kk * 64 + lg * 16);

#pragma unroll
    for (int q = 0; q < 4; ++q) {
      bf16x8 af[2][2];
#pragma unroll
      for (int m2 = 0; m2 < 2; ++m2)
#pragma unroll
        for (int kk = 0; kk < 2; ++kk)
          af[m2][kk] = LDF(as, wr * 128 + (q * 2 + m2) * 16 + lr, kk * 64 + lg * 16);
      __builtin_amdgcn_s_setprio(1);
#pragma unroll
      for (int m2 = 0; m2 < 2; ++m2)
#pragma unroll
        for (int kk = 0; kk < 2; ++kk)
#pragma unroll
          for (int nf = 0; nf < 4; ++nf)
            acc[q * 2 + m2][nf] = __builtin_amdgcn_mfma_f32_16x16x32_bf16(
                af[m2][kk], bfrag[nf][kk], acc[q * 2 + m2][nf], 0, 0, 0);
      __builtin_amdgcn_s_setprio(0);
    }
    __syncthreads();   // drains prefetch vmcnt (issued ~1 tile of compute ago) + LDS handoff
  }

  // epilogue: C/D layout col=lane&15, row=(lane>>4)*4+reg
  float bv[4];
#pragma unroll
  for (int nf = 0; nf < 4; ++nf) bv[nf] = bias[bn + wcol * 64 + nf * 16 + lr];
#pragma unroll
  for (int mf = 0; mf < 8; ++mf) {
    const int row0 = bm + wr * 128 + mf * 16 + lg * 4;
#pragma unroll
    for (int nf = 0; nf < 4; ++nf) {
      const int col = bn + wcol * 64 + nf * 16 + lr;
#pragma unroll
      for (int r = 0; r < 4; ++r)
        C[(size_t)(row0 + r) * N + col] = acc[mf][nf][r] + bv[nf];
    }
  }
}

// ---------------- split-K K/V projection: 8 z-blocks = {K,V} x 4 K-chunks of 1024 -------
__global__ __launch_bounds__(256) void gemm_kv_splitk(
    const u16* __restrict__ Sb, const u16* __restrict__ Vbi,
    const u16* __restrict__ WkT, const u16* __restrict__ WvT,
    float* __restrict__ part) {
  const int z = blockIdx.z;
  const u16* A = (z >> 2) ? Vbi : Sb;
  const u16* B = (z >> 2) ? WvT : WkT;
  float* C = part + (size_t)z * (1024 * 768);
  const int kofs = (z & 3) * 1024;

  __shared__ u16 As[128 * 32];
  __shared__ u16 Bs[128 * 32];
  const int tid = threadIdx.x, w = tid >> 6, lane = tid & 63;
  const int lr = lane & 15, lg = lane >> 4;
  const int bm = blockIdx.y * 128, bn = blockIdx.x * 128;
  const int wr = (w >> 1) * 64, wc = (w & 1) * 64;
  f32x4 acc[4][4] = {};

  for (int kt = 0; kt < 32; ++kt) {
#pragma unroll
    for (int j = 0; j < 2; ++j) {
      int cb = j * 256 + w * 64;
      int c = cb + lane;
      const u16* gA = A + (size_t)(bm + (c >> 2)) * 4096 + kofs + kt * 32 + (c & 3) * 8;
      __builtin_amdgcn_global_load_lds((gld_src_t)(const void*)gA,
                                       (gld_dst_t)(As + (size_t)cb * 8), 16, 0, 0);
      const u16* gB = B + (size_t)(bn + (c >> 2)) * 4096 + kofs + kt * 32 + (c & 3) * 8;
      __builtin_amdgcn_global_load_lds((gld_src_t)(const void*)gB,
                                       (gld_dst_t)(Bs + (size_t)cb * 8), 16, 0, 0);
    }
    __syncthreads();
    bf16x8 af[4], bfr[4];
#pragma unroll
    for (int m = 0; m < 4; ++m)
      af[m] = *(const bf16x8*)(As + (wr + m * 16 + lr) * 32 + lg * 8);
#pragma unroll
    for (int n = 0; n < 4; ++n)
      bfr[n] = *(const bf16x8*)(Bs + (wc + n * 16 + lr) * 32 + lg * 8);
#pragma unroll
    for (int m = 0; m < 4; ++m)
#pragma unroll
      for (int n = 0; n < 4; ++n)
        acc[m][n] = __builtin_amdgcn_mfma_f32_16x16x32_bf16(af[m], bfr[n], acc[m][n], 0, 0, 0);
    __syncthreads();
  }
#pragma unroll
  for (int n = 0; n < 4; ++n) {
    int col = bn + wc + n * 16 + lr;
#pragma unroll
    for (int m = 0; m < 4; ++m) {
      int row0 = bm + wr + m * 16 + lg * 4;
#pragma unroll
      for (int r = 0; r < 4; ++r)
        C[(size_t)(row0 + r) * 768 + col] = acc[m][n][r];
    }
  }
}

// ---------------- split-K reduce: partials + bias -> bf16 Kp / Vp ----------------------
__global__ __launch_bounds__(256) void kv_reduce(const float* __restrict__ part,
                                                 const float* __restrict__ bk,
                                                 const float* __restrict__ bv,
                                                 u16* __restrict__ Kp, u16* __restrict__ Vp) {
  const int mat = blockIdx.y;
  const long e = ((long)blockIdx.x * 256 + threadIdx.x) * 4;
  const float* p0 = part + (size_t)mat * 4 * 786432 + e;
  fvec4 s = *(const fvec4*)p0;
  s += *(const fvec4*)(p0 + 786432);
  s += *(const fvec4*)(p0 + 2 * 786432);
  s += *(const fvec4*)(p0 + 3 * 786432);
  const float* bias = mat ? bv : bk;
  int col = (int)(e % 768);
  fvec4 bb = *(const fvec4*)(bias + col);
  s += bb;
  u16x4 o;
  o[0] = bf16_rne(s[0]); o[1] = bf16_rne(s[1]); o[2] = bf16_rne(s[2]); o[3] = bf16_rne(s[3]);
  u16* dst = mat ? Vp : Kp;
  *(u16x4*)(dst + e) = o;
}

// ---------------- swapped-QK^T flash attention (round 6, passed) ----------------
__global__ __launch_bounds__(256, 3) void attn_flash(
    const u16* __restrict__ Q,   // [8192, 768] bf16, pre-scaled
    const u16* __restrict__ Kb,  // [1024, 768] bf16 (rows >= 1000 are zero-padded)
    const u16* __restrict__ VT,  // [768, 1024] bf16
    u16* __restrict__ O) {       // [8192, 768] bf16
  constexpr int DM = 768, SPAD = 1024;
  __shared__ u16 Ks[2][64 * 64];
  __shared__ u16 VTs[2][64 * 64];

  const int tid = threadIdx.x, w = tid >> 6, lane = tid & 63;
  const int q5 = lane & 31, hi = lane >> 5, l7 = lane & 7;
  const int h = blockIdx.y;
  const int qrow = blockIdx.x * 128 + w * 32 + q5;

  bf16x8 qf[4];
#pragma unroll
  for (int dstep = 0; dstep < 4; ++dstep)
    qf[dstep] = *(const bf16x8*)(Q + (size_t)qrow * DM + h * 64 + dstep * 16 + hi * 8);

  auto STAGE = [&](int ch, int buf) {
#pragma unroll
    for (int it = 0; it < 2; ++it) {
      int slot = it * 256 + w * 64 + lane;
      int row = slot >> 3;
      int cg = (slot & 7) ^ (row & 7);
      __builtin_amdgcn_global_load_lds(
          (gld_src_t)(const void*)(Kb + (size_t)(ch * 64 + row) * DM + h * 64 + cg * 8),
          (gld_dst_t)(&Ks[buf][(size_t)(it * 256 + w * 64) * 8]), 16, 0, 0);
      __builtin_amdgcn_global_load_lds(
          (gld_src_t)(const void*)(VT + (size_t)(h * 64 + row) * SPAD + ch * 64 + cg * 8),
          (gld_dst_t)(&VTs[buf][(size_t)(it * 256 + w * 64) * 8]), 16, 0, 0);
    }
  };

  STAGE(0, 0);
  __syncthreads();

  float m_run = -3.0e38f, l_part = 0.0f;
  f32x16 oa0 = {}, oa1 = {};

  for (int ch = 0; ch < 16; ++ch) {
    const int cur = ch & 1;
    if (ch < 15) STAGE(ch + 1, cur ^ 1);

    const char* kbase = (const char*)&Ks[cur][0];
    const char* vbase = (const char*)&VTs[cur][0];

    f32x16 sc0 = {}, sc1 = {};
#pragma unroll
    for (int dstep = 0; dstep < 4; ++dstep) {
      const int colb = (dstep * 32 + hi * 16);
      bf16x8 kf0 = *(const bf16x8*)(kbase + (size_t)q5 * 128 + (colb ^ (l7 << 4)));
      bf16x8 kf1 = *(const bf16x8*)(kbase + (size_t)(32 + q5) * 128 + (colb ^ (l7 << 4)));
      sc0 = __builtin_amdgcn_mfma_f32_32x32x16_bf16(kf0, qf[dstep], sc0, 0, 0, 0);
      sc1 = __builtin_amdgcn_mfma_f32_32x32x16_bf16(kf1, qf[dstep], sc1, 0, 0, 0);
    }
    if (ch == 15) {
#pragma unroll
      for (int r = 4; r < 16; ++r) sc1[r] = -3.0e38f;
    }

    float mi = sc0[0];
#pragma unroll
    for (int r = 1; r < 16; ++r) mi = fmaxf(mi, sc0[r]);
#pragma unroll
    for (int r = 0; r < 16; ++r) mi = fmaxf(mi, sc1[r]);
    float cm = fmaxf(mi, __shfl_xor(mi, 32, 64));

    if (__any(cm > m_run + 8.0f)) {
      float mn = fmaxf(m_run, cm);
      float fsc = exp2_fast(m_run - mn);
      m_run = mn;
      l_part *= fsc;
#pragma unroll
      for (int r = 0; r < 16; ++r) { oa0[r] *= fsc; oa1[r] *= fsc; }
    }

#pragma unroll
    for (int r = 0; r < 16; ++r) {
      float p0 = exp2_fast(sc0[r] - m_run); l_part += p0; sc0[r] = p0;
      float p1 = exp2_fast(sc1[r] - m_run); l_part += p1; sc1[r] = p1;
    }

#pragma unroll
    for (int st = 0; st < 2; ++st) {
#pragma unroll
      for (int ks = 0; ks < 2; ++ks) {
        float pv0, pv1, pv2, pv3, pv4, pv5, pv6, pv7;
        if (st == 0) {
          if (ks == 0) { pv0=sc0[0];pv1=sc0[1];pv2=sc0[2];pv3=sc0[3];pv4=sc0[4];pv5=sc0[5];pv6=sc0[6];pv7=sc0[7]; }
          else         { pv0=sc0[8];pv1=sc0[9];pv2=sc0[10];pv3=sc0[11];pv4=sc0[12];pv5=sc0[13];pv6=sc0[14];pv7=sc0[15]; }
        } else {
          if (ks == 0) { pv0=sc1[0];pv1=sc1[1];pv2=sc1[2];pv3=sc1[3];pv4=sc1[4];pv5=sc1[5];pv6=sc1[6];pv7=sc1[7]; }
          else         { pv0=sc1[8];pv1=sc1[9];pv2=sc1[10];pv3=sc1[11];pv4=sc1[12];pv5=sc1[13];pv6=sc1[14];pv7=sc1[15]; }
        }
        uint32_t a = pk_bf16(pv0, pv1), b = pk_bf16(pv2, pv3);
        uint32_t c = pk_bf16(pv4, pv5), d = pk_bf16(pv6, pv7);
        uint32_t sa = (uint32_t)__shfl_xor((int)a, 32, 64);
        uint32_t sb = (uint32_t)__shfl_xor((int)b, 32, 64);
        uint32_t sc_ = (uint32_t)__shfl_xor((int)c, 32, 64);
        uint32_t sd = (uint32_t)__shfl_xor((int)d, 32, 64);
        u32x4 jw;
        jw[0] = hi ? sc_ : a;
        jw[1] = hi ? sd  : b;
        jw[2] = hi ? c   : sa;
        jw[3] = hi ? d   : sb;
        bf16x8 pB = __builtin_bit_cast(bf16x8, jw);
        const int colb = (st * 64 + ks * 32 + hi * 16);
#pragma unroll
        for (int dt = 0; dt < 2; ++dt) {
          bf16x8 vtf = *(const bf16x8*)(vbase + (size_t)(dt * 32 + q5) * 128 + (colb ^ (l7 << 4)));
          if (dt == 0) oa0 = __builtin_amdgcn_mfma_f32_32x32x16_bf16(vtf, pB, oa0, 0, 0, 0);
          else         oa1 = __builtin_amdgcn_mfma_f32_32x32x16_bf16(vtf, pB, oa1, 0, 0, 0);
        }
      }
    }
    __syncthreads();
  }

  float ool = 1.0f / (l_part + __shfl_xor(l_part, 32, 64));
  u16* obase = O + (size_t)qrow * DM + h * 64;
#pragma unroll
  for (int dt = 0; dt < 2; ++dt) {
#pragma unroll
    for (int g = 0; g < 4; ++g) {
      float v0, v1, v2, v3;
      if (dt == 0) { v0 = oa0[4*g]; v1 = oa0[4*g+1]; v2 = oa0[4*g+2]; v3 = oa0[4*g+3]; }
      else         { v0 = oa1[4*g]; v1 = oa1[4*g+1]; v2 = oa1[4*g+2]; v3 = oa1[4*g+3]; }
      u32x2 st2;
      st2[0] = pk_bf16(v0 * ool, v1 * ool);
      st2[1] = pk_bf16(v2 * ool, v3 * ool);
      *(u32x2*)(obase + dt * 32 + g * 8 + hi * 4) = st2;
    }
  }
}

// ---------------- host ----------------
extern "C" void kernel_launch(void* const* d_in, const int* in_sizes, int n_in,
                              void* d_out, int out_size, void* d_ws, size_t ws_size,
                              hipStream_t stream) {
  (void)in_sizes; (void)n_in; (void)out_size; (void)ws_size;
  const float* target = (const float*)d_in[0];
  const float* source = (const float*)d_in[1];
  const float* value  = (const float*)d_in[2];
  const float* Wq = (const float*)d_in[3];
  const float* bq = (const float*)d_in[4];
  const float* Wk = (const float*)d_in[5];
  const float* bk = (const float*)d_in[6];
  const float* Wv = (const float*)d_in[7];
  const float* bv = (const float*)d_in[8];
  const float* Wo = (const float*)d_in[9];
  const float* bo = (const float*)d_in[10];
  float* out = (float*)d_out;

  char* ws = (char*)d_ws;
  size_t off = 0;
  auto carve = [&](size_t bytes) { void* p = ws + off; off += (bytes + 255) & ~(size_t)255; return p; };
  u16* Xb  = (u16*)carve(8192ull * 768 * 2);
  u16* Sb  = (u16*)carve(1024ull * 4096 * 2);
  u16* Vbi = (u16*)carve(1024ull * 4096 * 2);
  u16* WqT = (u16*)carve(768ull * 768 * 2);
  u16* WkT = (u16*)carve(768ull * 4096 * 2);
  u16* WvT = (u16*)carve(768ull * 4096 * 2);
  u16* WoT = (u16*)carve(4096ull * 768 * 2);
  u16* Qb  = (u16*)carve(8192ull * 768 * 2);
  u16* Kp  = (u16*)carve(1024ull * 768 * 2);
  u16* Vp  = (u16*)carve(1024ull * 768 * 2);
  u16* VTp = (u16*)carve(768ull * 1024 * 2);
  u16* Ob  = (u16*)carve(8192ull * 768 * 2);

  const float SCL = 0.18033688011112042f;   // (1/8) * log2(e): exp2-domain scores

  convert_pad_bf16<<<2048, 256, 0, stream>>>(target, Xb, 8192, 768, (8192ll * 768) / 4);
  convert_pad_bf16<<<2048, 256, 0, stream>>>(source, Sb, 1000, 4096, (1024ll * 4096) / 4);
  convert_pad_bf16<<<2048, 256, 0, stream>>>(value,  Vbi, 1000, 4096, (1024ll * 4096) / 4);
  transpose_to_bf16<true><<<dim3(24, 24),  256, 0, stream>>>(Wq, WqT, 768, 768);
  transpose_to_bf16<true><<<dim3(24, 128), 256, 0, stream>>>(Wk, WkT, 4096, 768);
  transpose_to_bf16<true><<<dim3(24, 128), 256, 0, stream>>>(Wv, WvT, 4096, 768);
  transpose_to_bf16<true><<<dim3(128, 24), 256, 0, stream>>>(Wo, WoT, 768, 4096);

  gemm_kv_splitk<<<dim3(6, 8, 8), 256, 0, stream>>>(Sb, Vbi, WkT, WvT, out);
  kv_reduce<<<dim3(768, 2), 256, 0, stream>>>(out, bk, bv, Kp, Vp);
  transpose_to_bf16<false><<<dim3(24, 32), 256, 0, stream>>>(Vp, VTp, 1024, 768);

  // Q projection with exp2-domain scale folded in
  gemm_bt_128<u16><<<dim3(6, 64, 1), 256, 0, stream>>>(Xb, Xb, WqT, WqT, bq, bq, Qb, Qb,
                                                       8192, 768, 768, SCL);

  attn_flash<<<dim3(64, 12), 256, 0, stream>>>(Qb, Kp, VTp, Ob);

  // output projection -> fp32 d_out (256^2 pipelined kernel)
  gemm_bt_256<<<dim3(16, 32), 512, 0, stream>>>(Ob, WoT, bo, out, 8192, 4096, 768);
}